// Round 1
// 100.710 us; speedup vs baseline: 1.1681x; 1.1681x over previous
//
#include <hip/hip_runtime.h>
#include <math.h>

#define NB 8        // batches
#define NN 4096     // nodes
#define NE 131072   // edges
#define NF 64       // features
#define CAP 256     // bucket capacity per node (degree ~Poisson(32), max ~60)
#define PCAP 128    // per-wave LDS edge cache capacity
#define LRELU_ALPHA 0.2f

// float -> bf16 (RNE)
static __device__ __forceinline__ ushort bf16r(float x) {
  uint u = __float_as_uint(x);
  return (ushort)((u + 0x7fffu + ((u >> 16) & 1u)) >> 16);
}
// bf16 pair unpack (low / high half of a 32-bit word)
static __device__ __forceinline__ float bflo(int u) {
  return __uint_as_float(((uint)u) << 16);
}
static __device__ __forceinline__ float bfhi(int u) {
  return __uint_as_float(((uint)u) & 0xffff0000u);
}

// ---------------------------------------------------------------------------
// K1 (fused, independent halves):
//   blocks [0,1024):     Wh(bf16) = h@W, batch-interleaved layout Whb[n][b][f]
//                        so K2 can gather all 8 batches of a dst row in ONE
//                        coalesced 1 KiB load. Wave = 8 rows (4 waves/SIMD
//                        occupancy, up from 2); lane = output feature. Scores
//                        ssrc/sdst stored [n][b] for phase-1 coalescing.
//   blocks [1024,1536):  bucket-append edges by src: bucket[s*CAP+p]=(dst,w)
// ---------------------------------------------------------------------------
__global__ __launch_bounds__(256) void fused_gemm_append_kernel(
    const float* __restrict__ h, const float* __restrict__ W,
    const float* __restrict__ a, const int* __restrict__ src,
    const int* __restrict__ dst, const float* __restrict__ ew,
    ushort* __restrict__ Whb, float* __restrict__ ssrc,
    float* __restrict__ sdst, int* __restrict__ cnt,
    int2* __restrict__ bucket) {
  int tid = threadIdx.x;
  int blk = blockIdx.x;
  if (blk >= 1024) {
    int e = (blk - 1024) * 256 + tid;
    int s = src[e];
    int d = dst[e];
    float w = ew[e];
    int p = atomicAdd(&cnt[s], 1);
    if (p < CAP) bucket[s * CAP + p] = make_int2(d, __float_as_int(w));
    return;
  }
  int f = tid & 63;
  int wave = blk * 4 + (tid >> 6);  // 0..4095, 8 rows each
  // W column f -> registers (coalesced loads)
  float Wc[64];
#pragma unroll
  for (int k = 0; k < 64; k++) Wc[k] = W[k * 64 + f];
  float A1 = a[f];
  float A2 = a[64 + f];

  int row0 = __builtin_amdgcn_readfirstlane(wave) * 8;  // uniform
  int b = row0 >> 12;    // batch (8 | 4096, so constant across the 8 rows)
  int nb = row0 & 4095;  // node base
#pragma unroll 2
  for (int r = 0; r < 8; r++) {
    int row = row0 + r;  // uniform -> h loads go to scalar cache
    const float* hr = h + (size_t)row * NF;
    float ac0 = 0.f, ac1 = 0.f, ac2 = 0.f, ac3 = 0.f;
#pragma unroll
    for (int k = 0; k < 64; k += 4) {
      ac0 += hr[k] * Wc[k];
      ac1 += hr[k + 1] * Wc[k + 1];
      ac2 += hr[k + 2] * Wc[k + 2];
      ac3 += hr[k + 3] * Wc[k + 3];
    }
    float acc = (ac0 + ac1) + (ac2 + ac3);
    int n8b = (nb + r) * 8 + b;  // batch-interleaved row index
    Whb[(size_t)n8b * NF + f] = bf16r(acc);
    float v1 = acc * A1;
    float v2 = acc * A2;
#pragma unroll
    for (int off = 1; off < 64; off <<= 1) {
      v1 += __shfl_xor(v1, off);
      v2 += __shfl_xor(v2, off);
    }
    if (f == 0) ssrc[n8b] = v1;
    if (f == 32) sdst[n8b] = v2;
  }
}

// ---------------------------------------------------------------------------
// K2: aggregation. Wave = one NODE across ALL 8 batches (was: one (b,n) pair).
//   Phase 1: lane = (edge-sub l>>3, batch l&7). exv for 8 edges x 8 batches
//            per iteration; LDS writes are lane-linear (conflict-free);
//            bucket read ONCE per node (was 8x). Butterfly over stride-8
//            lanes gives all 8 denominators at once.
//   Phase 2: lane = (batch l>>3, fgroup l&7). Per edge: ONE coalesced 1 KiB
//            dwordx4 gather covers all 8 batches' Wh rows (8x fewer VMEM
//            instrs than per-batch 128B gathers), 8 bf16-unpack FMAs/lane.
//   No __syncthreads anywhere (wave-private LDS rows).
// ---------------------------------------------------------------------------
__global__ __launch_bounds__(256) void agg_kernel(
    const ushort* __restrict__ Whb, const float* __restrict__ ssrc,
    const float* __restrict__ sdst, const int* __restrict__ cnt,
    const int2* __restrict__ bucket, float* __restrict__ out) {
  __shared__ float pexv[4][PCAP * 8];  // 16 KiB: exv per (edge, batch)
  __shared__ int dste[4][PCAP];        // 2 KiB: dst per edge
  int tid = threadIdx.x;
  int w = tid >> 6;  // wave -> node within block
  int l = tid & 63;
  int n = blockIdx.x * 4 + w;
  int cntn = min(cnt[n], PCAP);

  // ---- phase 1: exv for all (edge, batch) pairs ----
  int es = l >> 3;  // edge sub-index
  int b1 = l & 7;   // batch
  float ss = ssrc[n * 8 + b1];
  const int2* bkt = bucket + n * CAP;
  float den = 0.f;
  for (int e0 = 0; e0 < cntn; e0 += 8) {
    int e = e0 + es;
    if (e < cntn) {
      int2 ed = bkt[e];  // 8 lanes/addr broadcast, one 64B line per iter
      float x = ss + sdst[ed.x * 8 + b1];  // 32B contiguous per edge
      x = (x > 0.f) ? x : LRELU_ALPHA * x;
      x *= __int_as_float(ed.y);
      float v = __expf(x);
      pexv[w][e * 8 + b1] = v;  // word index == e0*8 + l : lane-linear
      if (b1 == 0) dste[w][e] = ed.x;
      den += v;
    }
  }
  // reduce over edge-sub lanes (stride 8 shares batch b1)
  den += __shfl_xor(den, 8);
  den += __shfl_xor(den, 16);
  den += __shfl_xor(den, 32);

  // ---- phase 2: lane = (batch l>>3, feature group l&7) ----
  int b2 = l >> 3;
  int fi = l & 7;
  float dn = __shfl(den, b2);  // lane b2 holds batch b2's denominator
  const ushort* wp = Whb + l * 8;  // + d*512 => byte off d*1024 + l*16
  float acc0 = 0.f, acc1 = 0.f, acc2 = 0.f, acc3 = 0.f;
  float acc4 = 0.f, acc5 = 0.f, acc6 = 0.f, acc7 = 0.f;
  int e = 0;
  for (; e + 4 <= cntn; e += 4) {
    int4 dd = *(const int4*)&dste[w][e];  // one b128 broadcast: 4 dsts
    float ev0 = pexv[w][(e + 0) * 8 + b2];
    float ev1 = pexv[w][(e + 1) * 8 + b2];
    float ev2 = pexv[w][(e + 2) * 8 + b2];
    float ev3 = pexv[w][(e + 3) * 8 + b2];
    int4 q0 = *(const int4*)(wp + (size_t)dd.x * 512);  // 1 KiB coalesced
    int4 q1 = *(const int4*)(wp + (size_t)dd.y * 512);
    int4 q2 = *(const int4*)(wp + (size_t)dd.z * 512);
    int4 q3 = *(const int4*)(wp + (size_t)dd.w * 512);
    acc0 += ev0 * bflo(q0.x); acc1 += ev0 * bfhi(q0.x);
    acc2 += ev0 * bflo(q0.y); acc3 += ev0 * bfhi(q0.y);
    acc4 += ev0 * bflo(q0.z); acc5 += ev0 * bfhi(q0.z);
    acc6 += ev0 * bflo(q0.w); acc7 += ev0 * bfhi(q0.w);
    acc0 += ev1 * bflo(q1.x); acc1 += ev1 * bfhi(q1.x);
    acc2 += ev1 * bflo(q1.y); acc3 += ev1 * bfhi(q1.y);
    acc4 += ev1 * bflo(q1.z); acc5 += ev1 * bfhi(q1.z);
    acc6 += ev1 * bflo(q1.w); acc7 += ev1 * bfhi(q1.w);
    acc0 += ev2 * bflo(q2.x); acc1 += ev2 * bfhi(q2.x);
    acc2 += ev2 * bflo(q2.y); acc3 += ev2 * bfhi(q2.y);
    acc4 += ev2 * bflo(q2.z); acc5 += ev2 * bfhi(q2.z);
    acc6 += ev2 * bflo(q2.w); acc7 += ev2 * bfhi(q2.w);
    acc0 += ev3 * bflo(q3.x); acc1 += ev3 * bfhi(q3.x);
    acc2 += ev3 * bflo(q3.y); acc3 += ev3 * bfhi(q3.y);
    acc4 += ev3 * bflo(q3.z); acc5 += ev3 * bfhi(q3.z);
    acc6 += ev3 * bflo(q3.w); acc7 += ev3 * bfhi(q3.w);
  }
  for (; e < cntn; e++) {
    int d = dste[w][e];
    float ev = pexv[w][e * 8 + b2];
    int4 q = *(const int4*)(wp + (size_t)d * 512);
    acc0 += ev * bflo(q.x); acc1 += ev * bfhi(q.x);
    acc2 += ev * bflo(q.y); acc3 += ev * bfhi(q.y);
    acc4 += ev * bflo(q.z); acc5 += ev * bfhi(q.z);
    acc6 += ev * bflo(q.w); acc7 += ev * bfhi(q.w);
  }
  float inv = (cntn > 0) ? (1.0f / dn) : 0.f;
  float r0 = acc0 * inv, r1 = acc1 * inv, r2 = acc2 * inv, r3 = acc3 * inv;
  float r4 = acc4 * inv, r5 = acc5 * inv, r6 = acc6 * inv, r7 = acc7 * inv;
  r0 = (r0 > 0.f) ? r0 : expm1f(r0);
  r1 = (r1 > 0.f) ? r1 : expm1f(r1);
  r2 = (r2 > 0.f) ? r2 : expm1f(r2);
  r3 = (r3 > 0.f) ? r3 : expm1f(r3);
  r4 = (r4 > 0.f) ? r4 : expm1f(r4);
  r5 = (r5 > 0.f) ? r5 : expm1f(r5);
  r6 = (r6 > 0.f) ? r6 : expm1f(r6);
  r7 = (r7 > 0.f) ? r7 : expm1f(r7);
  size_t ob = ((size_t)(b2 * NN + n)) * NF + fi * 8;  // 256B/b-group contig
  *(float4*)(out + ob) = make_float4(r0, r1, r2, r3);
  *(float4*)(out + ob + 4) = make_float4(r4, r5, r6, r7);
}

// ---------------------------------------------------------------------------
extern "C" void kernel_launch(void* const* d_in, const int* in_sizes, int n_in,
                              void* d_out, int out_size, void* d_ws,
                              size_t ws_size, hipStream_t stream) {
  const float* h = (const float*)d_in[0];
  const int* edge_index = (const int*)d_in[1];
  const float* ew = (const float*)d_in[2];
  const float* W = (const float*)d_in[3];
  const float* a = (const float*)d_in[4];
  float* out = (float*)d_out;

  const int* src = edge_index;       // edge_index[0, :]
  const int* dst = edge_index + NE;  // edge_index[1, :]

  // Workspace layout (16B-aligned chunks):
  uint8_t* ws = (uint8_t*)d_ws;
  ushort* Whb = (ushort*)ws;                 // 4 MiB  (N*B*F bf16, [n][b][f])
  float* ssrc = (float*)(ws + 4194304);      // 128 KiB ([n][b])
  float* sdst = (float*)(ws + 4325376);      // 128 KiB ([n][b])
  int* cnt = (int*)(ws + 4456448);           // 16 KiB
  int2* bucket = (int2*)(ws + 4472832);      // 8 MiB  (N*CAP*8B)
  // total ~12.3 MiB

  hipMemsetAsync(cnt, 0, NN * sizeof(int), stream);
  fused_gemm_append_kernel<<<1536, 256, 0, stream>>>(h, W, a, src, dst, ew,
                                                     Whb, ssrc, sdst, cnt,
                                                     bucket);
  agg_kernel<<<NN / 4, 256, 0, stream>>>(Whb, ssrc, sdst, cnt, bucket, out);
}